// Round 14
// baseline (447.896 us; speedup 1.0000x reference)
//
#include <hip/hip_runtime.h>
#include <hip/hip_fp16.h>

// GDE func: out = MLP(relu(mean_agg(z,edges)@Wg + z@Ws + bg))
// Round 13 -> 14: fuse L3+L4 correctly (fix R10's three design errors):
// BN=128 4-wave blocks own the FULL 128x512 h3 row-panel -> no atomics,
// all waves write H3, 64x64 L4 tiles. Per cb: proven gemm_r phase-A core
// -> tanh into 32KB swizzled H3 (reuses dead As/Bs LDS) -> 16KB wt3
// k-slices -> L4 accumulates in oacc -> direct f32 store (+b3).
// Kills h3's 204MB HBM round-trip and the gemm4 dispatch.

typedef _Float16 f16;
typedef __attribute__((ext_vector_type(4))) _Float16 f16x4;
typedef __attribute__((ext_vector_type(8))) _Float16 f16x8;
typedef __attribute__((ext_vector_type(4))) float f32x4;

__device__ __forceinline__ void async_load16(const void* g, void* lds) {
  __builtin_amdgcn_global_load_lds(
      (const __attribute__((address_space(1))) void*)g,
      (__attribute__((address_space(3))) void*)lds, 16, 0, 0);
}

__device__ __forceinline__ float fast_tanh(float x) {
  float a = fabsf(x);
  float e = __expf(-2.0f * a);
  float r = (1.0f - e) * __builtin_amdgcn_rcpf(1.0f + e);
  return copysignf(r, x);
}

__global__ __launch_bounds__(256) void zero_kernel(int* __restrict__ p, int n) {
  int i = blockIdx.x * 256 + threadIdx.x;
  int stride = gridDim.x * 256;
  for (; i < n; i += stride) p[i] = 0;
}

// ---- CSR scan ----
__global__ __launch_bounds__(256) void scan_partial(const int* __restrict__ degi,
                                                    int* __restrict__ bsum, int N) {
  __shared__ int lds[256];
  int b = blockIdx.x, t = threadIdx.x;
  int s = 0;
#pragma unroll
  for (int j = 0; j < 4; ++j) {
    int idx = b * 1024 + t * 4 + j;
    if (idx < N) s += degi[idx];
  }
  lds[t] = s;
  __syncthreads();
  for (int off = 128; off > 0; off >>= 1) {
    if (t < off) lds[t] += lds[t + off];
    __syncthreads();
  }
  if (t == 0) bsum[b] = lds[0];
}

__global__ void scan_bsums(const int* __restrict__ bsum, int* __restrict__ boff,
                           int* __restrict__ row_start, int nb, int N) {
  if (threadIdx.x == 0 && blockIdx.x == 0) {
    int acc = 0;
    for (int i = 0; i < nb; ++i) { boff[i] = acc; acc += bsum[i]; }
    row_start[N] = acc;  // == E
  }
}

__global__ __launch_bounds__(256) void scan_final(
    const int* __restrict__ degi, const int* __restrict__ boff,
    int* __restrict__ row_start, int* __restrict__ cursor, int N) {
  __shared__ int lds[256];
  int b = blockIdx.x, t = threadIdx.x;
  int base = b * 1024;
  int v[4];
  int s = 0;
#pragma unroll
  for (int j = 0; j < 4; ++j) {
    int idx = base + t * 4 + j;
    v[j] = (idx < N) ? degi[idx] : 0;
    s += v[j];
  }
  lds[t] = s;
  __syncthreads();
  for (int off = 1; off < 256; off <<= 1) {
    int x = lds[t];
    int y = (t >= off) ? lds[t - off] : 0;
    __syncthreads();
    lds[t] = x + y;
    __syncthreads();
  }
  int pre = boff[b] + lds[t] - s;
#pragma unroll
  for (int j = 0; j < 4; ++j) {
    int idx = base + t * 4 + j;
    if (idx < N) { row_start[idx] = pre; cursor[idx] = pre; pre += v[j]; }
  }
}

__global__ __launch_bounds__(256) void fill_adj(const int* __restrict__ src,
                                                const int* __restrict__ dst,
                                                int* __restrict__ cursor,
                                                int* __restrict__ adj, int E) {
  int e = blockIdx.x * 256 + threadIdx.x;
  if (e >= E) return;
  int p = atomicAdd(&cursor[dst[e]], 1);
  adj[p] = src[e];
}

// ---- merged: deg_count + weight prep + z16 cast (+Xc z-half) ----
__global__ __launch_bounds__(256) void fused_prep(
    const int* __restrict__ dst, int* __restrict__ degi, int E,
    const float* __restrict__ Wg, const float* __restrict__ Ws,
    const float* __restrict__ W1, const float* __restrict__ W2,
    const float* __restrict__ W3, f16* __restrict__ wgs, f16* __restrict__ wt1,
    f16* __restrict__ wt2, f16* __restrict__ wt3,
    const float* __restrict__ z, f16* __restrict__ z16, f16* __restrict__ Xc,
    int n4) {
  int i0 = blockIdx.x * 256 + threadIdx.x;
  int stride = gridDim.x * 256;
  for (int i = i0; i < n4; i += stride) {
    float4 v = *(const float4*)(z + 4 * (long long)i);
    f16x4 c;
    c[0] = (f16)v.x; c[1] = (f16)v.y; c[2] = (f16)v.z; c[3] = (f16)v.w;
    *(f16x4*)(z16 + 4 * (long long)i) = c;
    int node = i >> 5, sl = i & 31;
    *(f16x4*)(Xc + (long long)node * 256 + 128 + 4 * sl) = c;
  }
  for (int i = i0; i < E; i += stride) atomicAdd(&degi[dst[i]], 1);
  for (int i = i0; i < 425984; i += stride) {
    if (i < 32768) {
      int n = i >> 8, k = i & 255;
      wgs[i] = (f16)((k < 128) ? Wg[k * 128 + n] : Ws[(k - 128) * 128 + n]);
    } else if (i < 98304) {
      int j = i - 32768, c = j >> 7, k = j & 127;
      wt1[j] = (f16)W1[k * 512 + c];
    } else if (i < 360448) {
      int j = i - 98304, c = j >> 9, k = j & 511;
      wt2[j] = (f16)W2[k * 512 + c];
    } else {
      int j = i - 360448, c = j >> 9, k = j & 511;
      wt3[j] = (f16)W3[k * 128 + c];
    }
  }
}

// ---- gather + mean -> Xc mean-half: 32 lanes/node, masked 8-wide batch ----
__global__ __launch_bounds__(256) void gather_xcat(
    const f16* __restrict__ z16, const int* __restrict__ row_start,
    const int* __restrict__ adj, f16* __restrict__ Xc, int N) {
  int node = (blockIdx.x * 256 + threadIdx.x) >> 5;
  if (node >= N) return;
  int lane = threadIdx.x & 31;
  int beg = row_start[node], end = row_start[node + 1];
  float a0 = 0, a1 = 0, a2 = 0, a3 = 0;
#pragma unroll
  for (int j = 0; j < 8; ++j) {
    int idx = beg + j;
    bool vld = idx < end;
    int nb = vld ? adj[idx] : node;
    f16x4 x = *(const f16x4*)(z16 + (long long)nb * 128 + 4 * lane);
    float w = vld ? 1.0f : 0.0f;
    a0 += w * (float)x[0]; a1 += w * (float)x[1];
    a2 += w * (float)x[2]; a3 += w * (float)x[3];
  }
  int i = beg + 8;
  if (i < end) {
    float b0 = 0, b1 = 0, b2 = 0, b3 = 0;
    float c0 = 0, c1 = 0, c2 = 0, c3 = 0;
    float d0 = 0, d1 = 0, d2 = 0, d3 = 0;
    for (; i + 4 <= end; i += 4) {
      int n0 = adj[i], n1 = adj[i + 1], n2 = adj[i + 2], n3 = adj[i + 3];
      f16x4 v0 = *(const f16x4*)(z16 + (long long)n0 * 128 + 4 * lane);
      f16x4 v1 = *(const f16x4*)(z16 + (long long)n1 * 128 + 4 * lane);
      f16x4 v2 = *(const f16x4*)(z16 + (long long)n2 * 128 + 4 * lane);
      f16x4 v3 = *(const f16x4*)(z16 + (long long)n3 * 128 + 4 * lane);
      a0 += (float)v0[0]; a1 += (float)v0[1]; a2 += (float)v0[2]; a3 += (float)v0[3];
      b0 += (float)v1[0]; b1 += (float)v1[1]; b2 += (float)v1[2]; b3 += (float)v1[3];
      c0 += (float)v2[0]; c1 += (float)v2[1]; c2 += (float)v2[2]; c3 += (float)v2[3];
      d0 += (float)v3[0]; d1 += (float)v3[1]; d2 += (float)v3[2]; d3 += (float)v3[3];
    }
    for (; i < end; ++i) {
      f16x4 v = *(const f16x4*)(z16 + (long long)adj[i] * 128 + 4 * lane);
      a0 += (float)v[0]; a1 += (float)v[1]; a2 += (float)v[2]; a3 += (float)v[3];
    }
    a0 += b0 + c0 + d0; a1 += b1 + c1 + d1;
    a2 += b2 + c2 + d2; a3 += b3 + c3 + d3;
  }
  int dg = end - beg;
  float inv = 1.0f / (float)(dg > 1 ? dg : 1);
  long long o = (long long)node * 256;
  f16x4 m;
  m[0] = (f16)(a0 * inv); m[1] = (f16)(a1 * inv);
  m[2] = (f16)(a2 * inv); m[3] = (f16)(a3 * inv);
  *(f16x4*)(Xc + o + 4 * lane) = m;
}

// --------- R5/R11 proven drain GEMM (BK=64, single buffer, swizzled) ----------
template <int K, int NOUT, int WM, int WN, int MI, int ACT, bool OUTF32>
__global__ __launch_bounds__(WM * WN * 64) void gemm_r(
    const f16* __restrict__ X, const f16* __restrict__ Wt,
    const float* __restrict__ bias, void* __restrict__ OutV, int M) {
  constexpr int NJ = 4;
  constexpr int BM = WM * MI * 16;
  constexpr int BN = WN * NJ * 16;
  constexpr int NTHR = WM * WN * 64;
  constexpr int CA = (BM * 128) / (NTHR * 16);
  constexpr int CB = (BN * 128) / (NTHR * 16);
  __shared__ __align__(16) f16 As[BM * 64];
  __shared__ __align__(16) f16 Bs[BN * 64];

  const int tid = threadIdx.x;
  const int wid = tid >> 6, lane = tid & 63;
  const int wm = wid / WN, wn = wid % WN;
  const int lr = lane & 15, lq = lane >> 4;
  const int rxor = lr & 7;
  const long long m0 = (long long)blockIdx.x * BM;
  const int n0 = blockIdx.y * BN;

  const f16* Ag = X + m0 * K;
  const f16* Bg = Wt + (long long)n0 * K;

  long long aOff[CA], bOff[CB];
#pragma unroll
  for (int c = 0; c < CA; ++c) {
    int f = c * NTHR + tid;
    int row = f >> 3, ss = (f & 7) ^ (row & 7);
    aOff[c] = (long long)row * K + ss * 8;
  }
#pragma unroll
  for (int c = 0; c < CB; ++c) {
    int f = c * NTHR + tid;
    int row = f >> 3, ss = (f & 7) ^ (row & 7);
    bOff[c] = (long long)row * K + ss * 8;
  }

  f32x4 acc[MI][NJ];
#pragma unroll
  for (int i = 0; i < MI; ++i)
#pragma unroll
    for (int j = 0; j < NJ; ++j)
#pragma unroll
      for (int r = 0; r < 4; ++r) acc[i][j][r] = 0.0f;

#pragma unroll 1
  for (int k0 = 0; k0 < K; k0 += 64) {
#pragma unroll
    for (int c = 0; c < CA; ++c)
      async_load16(Ag + aOff[c] + k0, (char*)As + c * NTHR * 16 + wid * 1024);
#pragma unroll
    for (int c = 0; c < CB; ++c)
      async_load16(Bg + bOff[c] + k0, (char*)Bs + c * NTHR * 16 + wid * 1024);
    __syncthreads();
#pragma unroll
    for (int kk = 0; kk < 64; kk += 32) {
      const int co = (((kk >> 3) + lq) ^ rxor) * 16;
      f16x8 a[MI], b[NJ];
#pragma unroll
      for (int i = 0; i < MI; ++i)
        a[i] = *reinterpret_cast<const f16x8*>(
            (const char*)As + (wm * MI * 16 + i * 16 + lr) * 128 + co);
#pragma unroll
      for (int j = 0; j < NJ; ++j)
        b[j] = *reinterpret_cast<const f16x8*>(
            (const char*)Bs + (wn * NJ * 16 + j * 16 + lr) * 128 + co);
#pragma unroll
      for (int i = 0; i < MI; ++i)
#pragma unroll
        for (int j = 0; j < NJ; ++j)
          acc[i][j] = __builtin_amdgcn_mfma_f32_16x16x32_f16(a[i], b[j], acc[i][j], 0, 0, 0);
    }
    __syncthreads();
  }

#pragma unroll
  for (int i = 0; i < MI; ++i) {
#pragma unroll
    for (int j = 0; j < NJ; ++j) {
      int col = n0 + wn * NJ * 16 + j * 16 + lr;
      float bv = bias[col];
#pragma unroll
      for (int r = 0; r < 4; ++r) {
        long long row = m0 + wm * MI * 16 + i * 16 + lq * 4 + r;
        if (row < M) {
          float v = acc[i][j][r] + bv;
          if (ACT == 1) v = fmaxf(v, 0.0f);
          else if (ACT == 2) v = fast_tanh(v);
          if constexpr (OUTF32)
            ((float*)OutV)[row * NOUT + col] = v;
          else
            ((f16*)OutV)[row * NOUT + col] = (f16)v;
        }
      }
    }
  }
}

// ================== fused L3+L4 (no h3 in HBM, no atomics) ==================
// Block = 128-row panel, 4 waves (2x2, 64x64). For cb in 0..3:
//   phase A: h3cb = tanh(h2[panel] @ wt2[cb*128..]^T + b2)  (gemm_r core)
//   all waves write h3cb -> swizzled H3 in L[0,32K) (As/Bs region, dead)
//   for ks in 0..1: stage wt3 16KB k-slice -> L[32K,48K); L4 MFMA -> oacc
// Epilogue: out = oacc + b3 (f32 direct store).
__global__ __launch_bounds__(256) void fused34(
    const f16* __restrict__ h2, const f16* __restrict__ wt2,
    const f16* __restrict__ wt3, const float* __restrict__ b2,
    const float* __restrict__ b3, float* __restrict__ out, int M) {
  __shared__ __align__(16) char L[49152];
  const int tid = threadIdx.x;
  const int wid = tid >> 6, lane = tid & 63;
  const int wm = wid & 1, wn = wid >> 1;  // 2x2
  const int lr = lane & 15, lq = lane >> 4;
  const int key = lr & 7;
  const long long m0 = (long long)blockIdx.x * 128;
  const f16* Ag = h2 + m0 * 512;

  // shared stage offsets: all three matrices have row-stride 512 f16
  long long sOff[4];
#pragma unroll
  for (int c = 0; c < 4; ++c) {
    int f = c * 256 + tid;
    int row = f >> 3, ss = (f & 7) ^ (row & 7);
    sOff[c] = (long long)row * 512 + ss * 8;
  }

  f32x4 oacc[4][4];
#pragma unroll
  for (int i = 0; i < 4; ++i)
#pragma unroll
    for (int j = 0; j < 4; ++j)
#pragma unroll
      for (int r = 0; r < 4; ++r) oacc[i][j][r] = 0.0f;

#pragma unroll 1
  for (int cb = 0; cb < 4; ++cb) {
    const f16* Bg = wt2 + (long long)(cb * 128) * 512;
    f32x4 acc[4][4];
#pragma unroll
    for (int i = 0; i < 4; ++i)
#pragma unroll
      for (int j = 0; j < 4; ++j)
#pragma unroll
        for (int r = 0; r < 4; ++r) acc[i][j][r] = 0.0f;

    // ---- phase A: K=512 drain GEMM (BM=128, BN=128) ----
#pragma unroll 1
    for (int k0 = 0; k0 < 512; k0 += 64) {
#pragma unroll
      for (int c = 0; c < 4; ++c)
        async_load16(Ag + sOff[c] + k0, L + c * 4096 + wid * 1024);
#pragma unroll
      for (int c = 0; c < 4; ++c)
        async_load16(Bg + sOff[c] + k0, L + 16384 + c * 4096 + wid * 1024);
      __syncthreads();
#pragma unroll
      for (int kk = 0; kk < 64; kk += 32) {
        const int co = (((kk >> 3) + lq) ^ key) * 16;
        f16x8 a[4], b[4];
#pragma unroll
        for (int i = 0; i < 4; ++i)
          a[i] = *reinterpret_cast<const f16x8*>(L + (wm * 64 + i * 16 + lr) * 128 + co);
#pragma unroll
        for (int j = 0; j < 4; ++j)
          b[j] = *reinterpret_cast<const f16x8*>(L + 16384 + (wn * 64 + j * 16 + lr) * 128 + co);
#pragma unroll
        for (int i = 0; i < 4; ++i)
#pragma unroll
          for (int j = 0; j < 4; ++j)
            acc[i][j] = __builtin_amdgcn_mfma_f32_16x16x32_f16(a[i], b[j], acc[i][j], 0, 0, 0);
      }
      __syncthreads();
    }

    // ---- all waves write tanh'd quarter -> swizzled H3 [128][128] in [0,32K) ----
#pragma unroll
    for (int i = 0; i < 4; ++i)
#pragma unroll
      for (int j = 0; j < 4; ++j) {
        int col = wn * 64 + j * 16 + lr;
        float bv = b2[cb * 128 + col];
#pragma unroll
        for (int r = 0; r < 4; ++r) {
          int row = wm * 64 + i * 16 + lq * 4 + r;
          *reinterpret_cast<f16*>(L + row * 256 + (((col >> 3) ^ (row & 7)) << 4) +
                                  (col & 7) * 2) = (f16)fast_tanh(acc[i][j][r] + bv);
        }
      }
    __syncthreads();

    // ---- L4 partial: oacc += H3 @ wt3[:, cb*128..]^T, two 64-k slices ----
#pragma unroll 1
    for (int ks = 0; ks < 2; ++ks) {
#pragma unroll
      for (int c = 0; c < 4; ++c)
        async_load16(wt3 + sOff[c] + cb * 128 + ks * 64,
                     L + 32768 + c * 4096 + wid * 1024);
      __syncthreads();
#pragma unroll
      for (int kk = 0; kk < 64; kk += 32) {
        const int aco = ((ks * 8 + (kk >> 3) + lq) ^ key) * 16;
        const int bco = (((kk >> 3) + lq) ^ key) * 16;
        f16x8 a[4], b[4];
#pragma unroll
        for (int i = 0; i < 4; ++i)
          a[i] = *reinterpret_cast<const f16x8*>(L + (wm * 64 + i * 16 + lr) * 256 + aco);
#pragma unroll
        for (int j = 0; j < 4; ++j)
          b[j] = *reinterpret_cast<const f16x8*>(L + 32768 + (wn * 64 + j * 16 + lr) * 128 + bco);
#pragma unroll
        for (int i = 0; i < 4; ++i)
#pragma unroll
          for (int j = 0; j < 4; ++j)
            oacc[i][j] = __builtin_amdgcn_mfma_f32_16x16x32_f16(a[i], b[j], oacc[i][j], 0, 0, 0);
      }
      __syncthreads();
    }
  }

  // ---- epilogue: out = oacc + b3 ----
#pragma unroll
  for (int i = 0; i < 4; ++i)
#pragma unroll
    for (int j = 0; j < 4; ++j) {
      int col = wn * 64 + j * 16 + lr;
      float bv = b3[col];
#pragma unroll
      for (int r = 0; r < 4; ++r) {
        long long row = m0 + wm * 64 + i * 16 + lq * 4 + r;
        if (row < M) out[row * 128 + col] = oacc[i][j][r] + bv;
      }
    }
}

extern "C" void kernel_launch(void* const* d_in, const int* in_sizes, int n_in,
                              void* d_out, int out_size, void* d_ws, size_t ws_size,
                              hipStream_t stream) {
  const float* z  = (const float*)d_in[0];
  const int*   ei = (const int*)d_in[1];
  const float* Wg = (const float*)d_in[2];
  const float* Ws = (const float*)d_in[3];
  const float* bg = (const float*)d_in[4];
  const float* W1 = (const float*)d_in[5];
  const float* b1 = (const float*)d_in[6];
  const float* W2 = (const float*)d_in[7];
  const float* b2 = (const float*)d_in[8];
  const float* W3 = (const float*)d_in[9];
  const float* b3 = (const float*)d_in[10];

  const int Nn = in_sizes[0] / 128;
  const int E  = in_sizes[1] / 2;
  const int* src = ei;
  const int* dst = ei + E;
  const int nb = (Nn + 1023) / 1024;
  const int gm128 = (Nn + 127) / 128;
  const long long Mpad = (long long)gm128 * 128;

  // workspace overlay (peak ~207 MB); h3 buffer no longer needed:
  //   [0, 51.2M)        Xc    (prep/gather -> gemm1)
  //   [51.2, 76.8M)     h1    (gemm1 -> gemm2)
  //   [76.8, ~106M)     CSR + z16 (dead after gather)
  //   [106M, 208.4M)    h2    (gemm2 -> fused34)
  //   [208.4M, ...)     prepped weights (~1.7 MB)
  char* base = (char*)d_ws;
  const size_t XCB = (size_t)Mpad * 256 * 2;
  const size_t H1B = (size_t)Mpad * 128 * 2;
  f16* Xc = (f16*)(base);
  f16* h1 = (f16*)(base + XCB);
  size_t off = XCB + H1B;
  auto alloc = [&](size_t b) -> void* {
    void* p = base + off;
    off += (b + 255) & ~(size_t)255;
    return p;
  };
  int* degi      = (int*)alloc((size_t)Nn * 4);
  int* row_start = (int*)alloc((size_t)(Nn + 1) * 4);
  int* cursor    = (int*)alloc((size_t)Nn * 4);
  int* adj       = (int*)alloc((size_t)(E + 8) * 4);  // +8 pad for masked batch
  int* bsum      = (int*)alloc((size_t)nb * 4);
  int* boff      = (int*)alloc((size_t)nb * 4);
  f16* z16       = (f16*)alloc((size_t)Nn * 128 * 2);
  f16* h2  = (f16*)alloc((size_t)Mpad * 512 * 2);
  f16* wgs = (f16*)alloc((size_t)128 * 256 * 2);
  f16* wt1 = (f16*)alloc((size_t)512 * 128 * 2);
  f16* wt2 = (f16*)alloc((size_t)512 * 512 * 2);
  f16* wt3 = (f16*)alloc((size_t)128 * 512 * 2);

  // CSR + prep
  zero_kernel<<<(Nn + 255) / 256, 256, 0, stream>>>(degi, Nn);
  fused_prep<<<2048, 256, 0, stream>>>(dst, degi, E, Wg, Ws, W1, W2, W3,
                                       wgs, wt1, wt2, wt3, z, z16, Xc, Nn * 32);
  scan_partial<<<nb, 256, 0, stream>>>(degi, bsum, Nn);
  scan_bsums<<<1, 64, 0, stream>>>(bsum, boff, row_start, nb, Nn);
  scan_final<<<nb, 256, 0, stream>>>(degi, boff, row_start, cursor, Nn);
  fill_adj<<<(E + 255) / 256, 256, 0, stream>>>(src, dst, cursor, adj, E);

  // gather mean-half
  {
    long long tot = (long long)Nn * 32;
    gather_xcat<<<(int)((tot + 255) / 256), 256, 0, stream>>>(z16, row_start, adj, Xc, Nn);
  }

  // GEMM chain: g1, g2 on proven gemm_r; L3+L4 fused.
  gemm_r<256, 128, 2, 2, 4, 1, false><<<dim3(gm128, 1), 256, 0, stream>>>(Xc, wgs, bg, (void*)h1, Nn);
  gemm_r<128, 512, 2, 4, 4, 2, false><<<dim3(gm128, 2), 512, 0, stream>>>(h1, wt1, b1, (void*)h2, Nn);
  fused34<<<gm128, 256, 0, stream>>>(h2, wt2, wt3, b2, b3, (float*)d_out, Nn);
}

// Round 15
// 322.973 us; speedup vs baseline: 1.3868x; 1.3868x over previous
//
#include <hip/hip_runtime.h>
#include <hip/hip_fp16.h>

// GDE func: out = MLP(relu(mean_agg(z,edges)@Wg + z@Ws + bg))
// Round 14 -> 15: revert fused34 (196 VGPR dual-accumulator -> 9% occupancy,
// 3rd fusion failure with that signature). Resurrect R10's fused12 instead:
// L1+L2 with h1 in 32KB LDS (single live accumulator at a time, 48KB LDS,
// normal VGPR) -- R10 data shows it was ~20-30us vs 58us for split g1+g2.
// Everything else = R13's proven parts (gemm_r g3/g4, masked-8 gather, z16).

typedef _Float16 f16;
typedef __attribute__((ext_vector_type(4))) _Float16 f16x4;
typedef __attribute__((ext_vector_type(8))) _Float16 f16x8;
typedef __attribute__((ext_vector_type(4))) float f32x4;

__device__ __forceinline__ void async_load16(const void* g, void* lds) {
  __builtin_amdgcn_global_load_lds(
      (const __attribute__((address_space(1))) void*)g,
      (__attribute__((address_space(3))) void*)lds, 16, 0, 0);
}

__device__ __forceinline__ float fast_tanh(float x) {
  float a = fabsf(x);
  float e = __expf(-2.0f * a);
  float r = (1.0f - e) * __builtin_amdgcn_rcpf(1.0f + e);
  return copysignf(r, x);
}

__global__ __launch_bounds__(256) void zero_kernel(int* __restrict__ p, int n) {
  int i = blockIdx.x * 256 + threadIdx.x;
  int stride = gridDim.x * 256;
  for (; i < n; i += stride) p[i] = 0;
}

// ---- CSR scan ----
__global__ __launch_bounds__(256) void scan_partial(const int* __restrict__ degi,
                                                    int* __restrict__ bsum, int N) {
  __shared__ int lds[256];
  int b = blockIdx.x, t = threadIdx.x;
  int s = 0;
#pragma unroll
  for (int j = 0; j < 4; ++j) {
    int idx = b * 1024 + t * 4 + j;
    if (idx < N) s += degi[idx];
  }
  lds[t] = s;
  __syncthreads();
  for (int off = 128; off > 0; off >>= 1) {
    if (t < off) lds[t] += lds[t + off];
    __syncthreads();
  }
  if (t == 0) bsum[b] = lds[0];
}

__global__ void scan_bsums(const int* __restrict__ bsum, int* __restrict__ boff,
                           int* __restrict__ row_start, int nb, int N) {
  if (threadIdx.x == 0 && blockIdx.x == 0) {
    int acc = 0;
    for (int i = 0; i < nb; ++i) { boff[i] = acc; acc += bsum[i]; }
    row_start[N] = acc;  // == E
  }
}

__global__ __launch_bounds__(256) void scan_final(
    const int* __restrict__ degi, const int* __restrict__ boff,
    int* __restrict__ row_start, int* __restrict__ cursor, int N) {
  __shared__ int lds[256];
  int b = blockIdx.x, t = threadIdx.x;
  int base = b * 1024;
  int v[4];
  int s = 0;
#pragma unroll
  for (int j = 0; j < 4; ++j) {
    int idx = base + t * 4 + j;
    v[j] = (idx < N) ? degi[idx] : 0;
    s += v[j];
  }
  lds[t] = s;
  __syncthreads();
  for (int off = 1; off < 256; off <<= 1) {
    int x = lds[t];
    int y = (t >= off) ? lds[t - off] : 0;
    __syncthreads();
    lds[t] = x + y;
    __syncthreads();
  }
  int pre = boff[b] + lds[t] - s;
#pragma unroll
  for (int j = 0; j < 4; ++j) {
    int idx = base + t * 4 + j;
    if (idx < N) { row_start[idx] = pre; cursor[idx] = pre; pre += v[j]; }
  }
}

__global__ __launch_bounds__(256) void fill_adj(const int* __restrict__ src,
                                                const int* __restrict__ dst,
                                                int* __restrict__ cursor,
                                                int* __restrict__ adj, int E) {
  int e = blockIdx.x * 256 + threadIdx.x;
  if (e >= E) return;
  int p = atomicAdd(&cursor[dst[e]], 1);
  adj[p] = src[e];
}

// ---- merged: deg_count + weight prep + z16 cast (+Xc z-half) ----
__global__ __launch_bounds__(256) void fused_prep(
    const int* __restrict__ dst, int* __restrict__ degi, int E,
    const float* __restrict__ Wg, const float* __restrict__ Ws,
    const float* __restrict__ W1, const float* __restrict__ W2,
    const float* __restrict__ W3, f16* __restrict__ wgs, f16* __restrict__ wt1,
    f16* __restrict__ wt2, f16* __restrict__ wt3,
    const float* __restrict__ z, f16* __restrict__ z16, f16* __restrict__ Xc,
    int n4) {
  int i0 = blockIdx.x * 256 + threadIdx.x;
  int stride = gridDim.x * 256;
  for (int i = i0; i < n4; i += stride) {
    float4 v = *(const float4*)(z + 4 * (long long)i);
    f16x4 c;
    c[0] = (f16)v.x; c[1] = (f16)v.y; c[2] = (f16)v.z; c[3] = (f16)v.w;
    *(f16x4*)(z16 + 4 * (long long)i) = c;
    int node = i >> 5, sl = i & 31;
    *(f16x4*)(Xc + (long long)node * 256 + 128 + 4 * sl) = c;
  }
  for (int i = i0; i < E; i += stride) atomicAdd(&degi[dst[i]], 1);
  for (int i = i0; i < 425984; i += stride) {
    if (i < 32768) {
      int n = i >> 8, k = i & 255;
      wgs[i] = (f16)((k < 128) ? Wg[k * 128 + n] : Ws[(k - 128) * 128 + n]);
    } else if (i < 98304) {
      int j = i - 32768, c = j >> 7, k = j & 127;
      wt1[j] = (f16)W1[k * 512 + c];
    } else if (i < 360448) {
      int j = i - 98304, c = j >> 9, k = j & 511;
      wt2[j] = (f16)W2[k * 512 + c];
    } else {
      int j = i - 360448, c = j >> 9, k = j & 511;
      wt3[j] = (f16)W3[k * 128 + c];
    }
  }
}

// ---- gather + mean -> Xc mean-half: 32 lanes/node, masked 8-wide batch ----
__global__ __launch_bounds__(256) void gather_xcat(
    const f16* __restrict__ z16, const int* __restrict__ row_start,
    const int* __restrict__ adj, f16* __restrict__ Xc, int N) {
  int node = (blockIdx.x * 256 + threadIdx.x) >> 5;
  if (node >= N) return;
  int lane = threadIdx.x & 31;
  int beg = row_start[node], end = row_start[node + 1];
  float a0 = 0, a1 = 0, a2 = 0, a3 = 0;
#pragma unroll
  for (int j = 0; j < 8; ++j) {
    int idx = beg + j;
    bool vld = idx < end;
    int nb = vld ? adj[idx] : node;
    f16x4 x = *(const f16x4*)(z16 + (long long)nb * 128 + 4 * lane);
    float w = vld ? 1.0f : 0.0f;
    a0 += w * (float)x[0]; a1 += w * (float)x[1];
    a2 += w * (float)x[2]; a3 += w * (float)x[3];
  }
  int i = beg + 8;
  if (i < end) {
    float b0 = 0, b1 = 0, b2 = 0, b3 = 0;
    float c0 = 0, c1 = 0, c2 = 0, c3 = 0;
    float d0 = 0, d1 = 0, d2 = 0, d3 = 0;
    for (; i + 4 <= end; i += 4) {
      int n0 = adj[i], n1 = adj[i + 1], n2 = adj[i + 2], n3 = adj[i + 3];
      f16x4 v0 = *(const f16x4*)(z16 + (long long)n0 * 128 + 4 * lane);
      f16x4 v1 = *(const f16x4*)(z16 + (long long)n1 * 128 + 4 * lane);
      f16x4 v2 = *(const f16x4*)(z16 + (long long)n2 * 128 + 4 * lane);
      f16x4 v3 = *(const f16x4*)(z16 + (long long)n3 * 128 + 4 * lane);
      a0 += (float)v0[0]; a1 += (float)v0[1]; a2 += (float)v0[2]; a3 += (float)v0[3];
      b0 += (float)v1[0]; b1 += (float)v1[1]; b2 += (float)v1[2]; b3 += (float)v1[3];
      c0 += (float)v2[0]; c1 += (float)v2[1]; c2 += (float)v2[2]; c3 += (float)v2[3];
      d0 += (float)v3[0]; d1 += (float)v3[1]; d2 += (float)v3[2]; d3 += (float)v3[3];
    }
    for (; i < end; ++i) {
      f16x4 v = *(const f16x4*)(z16 + (long long)adj[i] * 128 + 4 * lane);
      a0 += (float)v[0]; a1 += (float)v[1]; a2 += (float)v[2]; a3 += (float)v[3];
    }
    a0 += b0 + c0 + d0; a1 += b1 + c1 + d1;
    a2 += b2 + c2 + d2; a3 += b3 + c3 + d3;
  }
  int dg = end - beg;
  float inv = 1.0f / (float)(dg > 1 ? dg : 1);
  long long o = (long long)node * 256;
  f16x4 m;
  m[0] = (f16)(a0 * inv); m[1] = (f16)(a1 * inv);
  m[2] = (f16)(a2 * inv); m[3] = (f16)(a3 * inv);
  *(f16x4*)(Xc + o + 4 * lane) = m;
}

// ======================= fused L1+L2 (verbatim R10, passed) =======================
// h2[128p,512] = tanh( relu(Xc@wgs^T + bg) @ wt1^T + b1 ), per 128-row panel.
// 4 waves (2x2, 64x64). LDS 48KB: phase1 As[0,16K) Bs[16K,32K);
// H1(relu'd, swizzled) [0,32K); W1 slice [32K,48K). Single live accumulator.
__global__ __launch_bounds__(256) void fused12(
    const f16* __restrict__ Xc, const f16* __restrict__ wgs,
    const f16* __restrict__ wt1, const float* __restrict__ bg,
    const float* __restrict__ b1, f16* __restrict__ h2) {
  __shared__ __align__(16) char L[49152];
  const int tid = threadIdx.x;
  const int wid = tid >> 6, lane = tid & 63;
  const int wm = wid & 1, wn = wid >> 1;  // 2x2
  const int lr = lane & 15, lq = lane >> 4;
  const int key = lr & 7;
  const long long m0 = (long long)blockIdx.x * 128;
  const f16* Ag = Xc + m0 * 256;

  f32x4 acc[4][4];
#pragma unroll
  for (int i = 0; i < 4; ++i)
#pragma unroll
    for (int j = 0; j < 4; ++j)
#pragma unroll
      for (int r = 0; r < 4; ++r) acc[i][j][r] = 0.0f;

  // ---- phase 1: L1, K=256 ----
#pragma unroll 1
  for (int k0 = 0; k0 < 256; k0 += 64) {
#pragma unroll
    for (int c = 0; c < 4; ++c) {
      int f = c * 256 + tid;
      int row = f >> 3, ss = (f & 7) ^ (row & 7);
      async_load16(Ag + (long long)row * 256 + k0 + ss * 8, L + f * 16);
    }
#pragma unroll
    for (int c = 0; c < 4; ++c) {
      int f = c * 256 + tid;
      int row = f >> 3, ss = (f & 7) ^ (row & 7);
      async_load16(wgs + row * 256 + k0 + ss * 8, L + 16384 + f * 16);
    }
    __syncthreads();
#pragma unroll
    for (int kk = 0; kk < 64; kk += 32) {
      const int co = (((kk >> 3) + lq) ^ key) * 16;
      f16x8 a[4], b[4];
#pragma unroll
      for (int i = 0; i < 4; ++i)
        a[i] = *reinterpret_cast<const f16x8*>(L + (wm * 64 + i * 16 + lr) * 128 + co);
#pragma unroll
      for (int j = 0; j < 4; ++j)
        b[j] = *reinterpret_cast<const f16x8*>(L + 16384 + (wn * 64 + j * 16 + lr) * 128 + co);
#pragma unroll
      for (int i = 0; i < 4; ++i)
#pragma unroll
        for (int j = 0; j < 4; ++j)
          acc[i][j] = __builtin_amdgcn_mfma_f32_16x16x32_f16(a[i], b[j], acc[i][j], 0, 0, 0);
    }
    __syncthreads();
  }

  // acc -> H1 (relu + bg), swizzled [128][128] f16 at L[0,32K)
#pragma unroll
  for (int i = 0; i < 4; ++i)
#pragma unroll
    for (int j = 0; j < 4; ++j) {
      int col = wn * 64 + j * 16 + lr;
      float bv = bg[col];
#pragma unroll
      for (int r = 0; r < 4; ++r) {
        int row = wm * 64 + i * 16 + lq * 4 + r;
        float v = fmaxf(acc[i][j][r] + bv, 0.0f);
        *reinterpret_cast<f16*>(L + row * 256 + (((col >> 3) ^ (row & 7)) * 16) +
                                (col & 7) * 2) = (f16)v;
      }
    }
  __syncthreads();

  // ---- phase 2: L2, K=128 (from H1), per 128-col block ----
#pragma unroll 1
  for (int cb = 0; cb < 4; ++cb) {
#pragma unroll
    for (int i = 0; i < 4; ++i)
#pragma unroll
      for (int j = 0; j < 4; ++j)
#pragma unroll
        for (int r = 0; r < 4; ++r) acc[i][j][r] = 0.0f;

#pragma unroll 1
    for (int kc = 0; kc < 2; ++kc) {
#pragma unroll
      for (int c = 0; c < 4; ++c) {
        int f = c * 256 + tid;
        int row = f >> 3, ss = (f & 7) ^ (row & 7);
        async_load16(wt1 + (long long)(cb * 128 + row) * 128 + kc * 64 + ss * 8,
                     L + 32768 + f * 16);
      }
      __syncthreads();
#pragma unroll
      for (int kk = 0; kk < 64; kk += 32) {
        const int aslot = kc * 8 + (kk >> 3) + lq;
        const int bco = (((kk >> 3) + lq) ^ key) * 16;
        f16x8 a[4], b[4];
#pragma unroll
        for (int i = 0; i < 4; ++i)
          a[i] = *reinterpret_cast<const f16x8*>(
              L + (wm * 64 + i * 16 + lr) * 256 + (aslot ^ key) * 16);
#pragma unroll
        for (int j = 0; j < 4; ++j)
          b[j] = *reinterpret_cast<const f16x8*>(
              L + 32768 + (wn * 64 + j * 16 + lr) * 128 + bco);
#pragma unroll
        for (int i = 0; i < 4; ++i)
#pragma unroll
          for (int j = 0; j < 4; ++j)
            acc[i][j] = __builtin_amdgcn_mfma_f32_16x16x32_f16(a[i], b[j], acc[i][j], 0, 0, 0);
      }
      __syncthreads();
    }
#pragma unroll
    for (int i = 0; i < 4; ++i)
#pragma unroll
      for (int j = 0; j < 4; ++j) {
        int colg = cb * 128 + wn * 64 + j * 16 + lr;
        float bv = b1[colg];
#pragma unroll
        for (int r = 0; r < 4; ++r) {
          long long row = m0 + wm * 64 + i * 16 + lq * 4 + r;
          h2[row * 512 + colg] = (f16)fast_tanh(acc[i][j][r] + bv);
        }
      }
  }
}

// --------- R5/R11 proven drain GEMM (BK=64, single buffer, swizzled) ----------
template <int K, int NOUT, int WM, int WN, int MI, int ACT, bool OUTF32>
__global__ __launch_bounds__(WM * WN * 64) void gemm_r(
    const f16* __restrict__ X, const f16* __restrict__ Wt,
    const float* __restrict__ bias, void* __restrict__ OutV, int M) {
  constexpr int NJ = 4;
  constexpr int BM = WM * MI * 16;
  constexpr int BN = WN * NJ * 16;
  constexpr int NTHR = WM * WN * 64;
  constexpr int CA = (BM * 128) / (NTHR * 16);
  constexpr int CB = (BN * 128) / (NTHR * 16);
  __shared__ __align__(16) f16 As[BM * 64];
  __shared__ __align__(16) f16 Bs[BN * 64];

  const int tid = threadIdx.x;
  const int wid = tid >> 6, lane = tid & 63;
  const int wm = wid / WN, wn = wid % WN;
  const int lr = lane & 15, lq = lane >> 4;
  const int rxor = lr & 7;
  const long long m0 = (long long)blockIdx.x * BM;
  const int n0 = blockIdx.y * BN;

  const f16* Ag = X + m0 * K;
  const f16* Bg = Wt + (long long)n0 * K;

  long long aOff[CA], bOff[CB];
#pragma unroll
  for (int c = 0; c < CA; ++c) {
    int f = c * NTHR + tid;
    int row = f >> 3, ss = (f & 7) ^ (row & 7);
    aOff[c] = (long long)row * K + ss * 8;
  }
#pragma unroll
  for (int c = 0; c < CB; ++c) {
    int f = c * NTHR + tid;
    int row = f >> 3, ss = (f & 7) ^ (row & 7);
    bOff[c] = (long long)row * K + ss * 8;
  }

  f32x4 acc[MI][NJ];
#pragma unroll
  for (int i = 0; i < MI; ++i)
#pragma unroll
    for (int j = 0; j < NJ; ++j)
#pragma unroll
      for (int r = 0; r < 4; ++r) acc[i][j][r] = 0.0f;

#pragma unroll 1
  for (int k0 = 0; k0 < K; k0 += 64) {
#pragma unroll
    for (int c = 0; c < CA; ++c)
      async_load16(Ag + aOff[c] + k0, (char*)As + c * NTHR * 16 + wid * 1024);
#pragma unroll
    for (int c = 0; c < CB; ++c)
      async_load16(Bg + bOff[c] + k0, (char*)Bs + c * NTHR * 16 + wid * 1024);
    __syncthreads();
#pragma unroll
    for (int kk = 0; kk < 64; kk += 32) {
      const int co = (((kk >> 3) + lq) ^ rxor) * 16;
      f16x8 a[MI], b[NJ];
#pragma unroll
      for (int i = 0; i < MI; ++i)
        a[i] = *reinterpret_cast<const f16x8*>(
            (const char*)As + (wm * MI * 16 + i * 16 + lr) * 128 + co);
#pragma unroll
      for (int j = 0; j < NJ; ++j)
        b[j] = *reinterpret_cast<const f16x8*>(
            (const char*)Bs + (wn * NJ * 16 + j * 16 + lr) * 128 + co);
#pragma unroll
      for (int i = 0; i < MI; ++i)
#pragma unroll
        for (int j = 0; j < NJ; ++j)
          acc[i][j] = __builtin_amdgcn_mfma_f32_16x16x32_f16(a[i], b[j], acc[i][j], 0, 0, 0);
    }
    __syncthreads();
  }

#pragma unroll
  for (int i = 0; i < MI; ++i) {
#pragma unroll
    for (int j = 0; j < NJ; ++j) {
      int col = n0 + wn * NJ * 16 + j * 16 + lr;
      float bv = bias[col];
#pragma unroll
      for (int r = 0; r < 4; ++r) {
        long long row = m0 + wm * MI * 16 + i * 16 + lq * 4 + r;
        if (row < M) {
          float v = acc[i][j][r] + bv;
          if (ACT == 1) v = fmaxf(v, 0.0f);
          else if (ACT == 2) v = fast_tanh(v);
          if constexpr (OUTF32)
            ((float*)OutV)[row * NOUT + col] = v;
          else
            ((f16*)OutV)[row * NOUT + col] = (f16)v;
        }
      }
    }
  }
}

extern "C" void kernel_launch(void* const* d_in, const int* in_sizes, int n_in,
                              void* d_out, int out_size, void* d_ws, size_t ws_size,
                              hipStream_t stream) {
  const float* z  = (const float*)d_in[0];
  const int*   ei = (const int*)d_in[1];
  const float* Wg = (const float*)d_in[2];
  const float* Ws = (const float*)d_in[3];
  const float* bg = (const float*)d_in[4];
  const float* W1 = (const float*)d_in[5];
  const float* b1 = (const float*)d_in[6];
  const float* W2 = (const float*)d_in[7];
  const float* b2 = (const float*)d_in[8];
  const float* W3 = (const float*)d_in[9];
  const float* b3 = (const float*)d_in[10];

  const int Nn = in_sizes[0] / 128;
  const int E  = in_sizes[1] / 2;
  const int* src = ei;
  const int* dst = ei + E;
  const int nb = (Nn + 1023) / 1024;
  const int gm128 = (Nn + 127) / 128;
  const long long Mpad = (long long)gm128 * 128;

  // workspace overlay (peak ~207 MB), h1 slot removed:
  //   [0, 51.2M)        Xc    (prep/gather -> fused12)
  //   [51.2, ~81M)      CSR + z16 (dead after gather)
  //   [0, 102.4M)       h3    (gemm3 -> gemm4; overlays Xc+CSR+z16, all dead)
  //   [102.4, 204.8M)   h2    (fused12 -> gemm3)
  //   [204.8M, ...)     prepped weights (~1.7 MB)
  char* base = (char*)d_ws;
  const size_t XCB = (size_t)Mpad * 256 * 2;
  const size_t H3B = (size_t)Mpad * 512 * 2;
  f16* Xc = (f16*)(base);
  f16* h3 = (f16*)(base);
  size_t off = XCB;
  auto alloc = [&](size_t b) -> void* {
    void* p = base + off;
    off += (b + 255) & ~(size_t)255;
    return p;
  };
  int* degi      = (int*)alloc((size_t)Nn * 4);
  int* row_start = (int*)alloc((size_t)(Nn + 1) * 4);
  int* cursor    = (int*)alloc((size_t)Nn * 4);
  int* adj       = (int*)alloc((size_t)(E + 8) * 4);  // +8 pad for masked batch
  int* bsum      = (int*)alloc((size_t)nb * 4);
  int* boff      = (int*)alloc((size_t)nb * 4);
  f16* z16       = (f16*)alloc((size_t)Nn * 128 * 2);
  off = H3B;  // h2 after h3 span
  f16* h2  = (f16*)alloc((size_t)Mpad * 512 * 2);
  f16* wgs = (f16*)alloc((size_t)128 * 256 * 2);
  f16* wt1 = (f16*)alloc((size_t)512 * 128 * 2);
  f16* wt2 = (f16*)alloc((size_t)512 * 512 * 2);
  f16* wt3 = (f16*)alloc((size_t)128 * 512 * 2);

  // CSR + prep
  zero_kernel<<<(Nn + 255) / 256, 256, 0, stream>>>(degi, Nn);
  fused_prep<<<2048, 256, 0, stream>>>(dst, degi, E, Wg, Ws, W1, W2, W3,
                                       wgs, wt1, wt2, wt3, z, z16, Xc, Nn * 32);
  scan_partial<<<nb, 256, 0, stream>>>(degi, bsum, Nn);
  scan_bsums<<<1, 64, 0, stream>>>(bsum, boff, row_start, nb, Nn);
  scan_final<<<nb, 256, 0, stream>>>(degi, boff, row_start, cursor, Nn);
  fill_adj<<<(E + 255) / 256, 256, 0, stream>>>(src, dst, cursor, adj, E);

  // gather mean-half
  {
    long long tot = (long long)Nn * 32;
    gather_xcat<<<(int)((tot + 255) / 256), 256, 0, stream>>>(z16, row_start, adj, Xc, Nn);
  }

  // MLP: fused L1+L2, then proven split g3/g4.
  fused12<<<gm128, 256, 0, stream>>>(Xc, wgs, wt1, bg, b1, h2);
  gemm_r<512, 512, 2, 4, 4, 2, false><<<dim3(gm128, 2), 512, 0, stream>>>(h2, wt2, b2, (void*)h3, Nn);
  gemm_r<512, 128, 2, 2, 4, 0, true><<<dim3(gm128, 1), 256, 0, stream>>>(h3, wt3, b3, d_out, Nn);
}

// Round 16
// 318.104 us; speedup vs baseline: 1.4080x; 1.0153x over previous
//
#include <hip/hip_runtime.h>
#include <hip/hip_fp16.h>

// GDE func: out = MLP(relu(mean_agg(z,edges)@Wg + z@Ws + bg))
// Round 15 -> 16: occupancy-driven GEMM scale-up, same verified template:
//   gemm3: gemm_r<WM=4,WN=4> 1024thr BM=BN=256, 64KB LDS -> 32 waves/CU
//          (was 12); halves per-output B-staging.
//   gemm4: gemm_r<WM=4,WN=2> 512thr BM=256 -> 24 waves/CU.
// CSR trims: zero -> hipMemsetAsync; scan_bsums folded into scan_final
// (each block reduces bsum itself; row_start[N]=E known).
// fused12 / gather / prep unchanged (proven).

typedef _Float16 f16;
typedef __attribute__((ext_vector_type(4))) _Float16 f16x4;
typedef __attribute__((ext_vector_type(8))) _Float16 f16x8;
typedef __attribute__((ext_vector_type(4))) float f32x4;

__device__ __forceinline__ void async_load16(const void* g, void* lds) {
  __builtin_amdgcn_global_load_lds(
      (const __attribute__((address_space(1))) void*)g,
      (__attribute__((address_space(3))) void*)lds, 16, 0, 0);
}

__device__ __forceinline__ float fast_tanh(float x) {
  float a = fabsf(x);
  float e = __expf(-2.0f * a);
  float r = (1.0f - e) * __builtin_amdgcn_rcpf(1.0f + e);
  return copysignf(r, x);
}

// ---- CSR scan ----
__global__ __launch_bounds__(256) void scan_partial(const int* __restrict__ degi,
                                                    int* __restrict__ bsum, int N) {
  __shared__ int lds[256];
  int b = blockIdx.x, t = threadIdx.x;
  int s = 0;
#pragma unroll
  for (int j = 0; j < 4; ++j) {
    int idx = b * 1024 + t * 4 + j;
    if (idx < N) s += degi[idx];
  }
  lds[t] = s;
  __syncthreads();
  for (int off = 128; off > 0; off >>= 1) {
    if (t < off) lds[t] += lds[t + off];
    __syncthreads();
  }
  if (t == 0) bsum[b] = lds[0];
}

// scan_final with inlined block-offset reduction (replaces scan_bsums)
__global__ __launch_bounds__(256) void scan_final(
    const int* __restrict__ degi, const int* __restrict__ bsum,
    int* __restrict__ row_start, int* __restrict__ cursor, int nb, int N, int E) {
  __shared__ int lds[256];
  __shared__ int sboff;
  int b = blockIdx.x, t = threadIdx.x;
  // reduce bsum[0..b-1] across the block
  lds[t] = (t < b && t < nb) ? bsum[t] : 0;
  __syncthreads();
  for (int off = 128; off > 0; off >>= 1) {
    if (t < off) lds[t] += lds[t + off];
    __syncthreads();
  }
  if (t == 0) {
    sboff = lds[0];
    if (b == 0) row_start[N] = E;
  }
  __syncthreads();

  int base = b * 1024;
  int v[4];
  int s = 0;
#pragma unroll
  for (int j = 0; j < 4; ++j) {
    int idx = base + t * 4 + j;
    v[j] = (idx < N) ? degi[idx] : 0;
    s += v[j];
  }
  lds[t] = s;
  __syncthreads();
  for (int off = 1; off < 256; off <<= 1) {
    int x = lds[t];
    int y = (t >= off) ? lds[t - off] : 0;
    __syncthreads();
    lds[t] = x + y;
    __syncthreads();
  }
  int pre = sboff + lds[t] - s;
#pragma unroll
  for (int j = 0; j < 4; ++j) {
    int idx = base + t * 4 + j;
    if (idx < N) { row_start[idx] = pre; cursor[idx] = pre; pre += v[j]; }
  }
}

__global__ __launch_bounds__(256) void fill_adj(const int* __restrict__ src,
                                                const int* __restrict__ dst,
                                                int* __restrict__ cursor,
                                                int* __restrict__ adj, int E) {
  int e = blockIdx.x * 256 + threadIdx.x;
  if (e >= E) return;
  int p = atomicAdd(&cursor[dst[e]], 1);
  adj[p] = src[e];
}

// ---- merged: deg_count + weight prep + z16 cast (+Xc z-half) ----
__global__ __launch_bounds__(256) void fused_prep(
    const int* __restrict__ dst, int* __restrict__ degi, int E,
    const float* __restrict__ Wg, const float* __restrict__ Ws,
    const float* __restrict__ W1, const float* __restrict__ W2,
    const float* __restrict__ W3, f16* __restrict__ wgs, f16* __restrict__ wt1,
    f16* __restrict__ wt2, f16* __restrict__ wt3,
    const float* __restrict__ z, f16* __restrict__ z16, f16* __restrict__ Xc,
    int n4) {
  int i0 = blockIdx.x * 256 + threadIdx.x;
  int stride = gridDim.x * 256;
  for (int i = i0; i < n4; i += stride) {
    float4 v = *(const float4*)(z + 4 * (long long)i);
    f16x4 c;
    c[0] = (f16)v.x; c[1] = (f16)v.y; c[2] = (f16)v.z; c[3] = (f16)v.w;
    *(f16x4*)(z16 + 4 * (long long)i) = c;
    int node = i >> 5, sl = i & 31;
    *(f16x4*)(Xc + (long long)node * 256 + 128 + 4 * sl) = c;
  }
  for (int i = i0; i < E; i += stride) atomicAdd(&degi[dst[i]], 1);
  for (int i = i0; i < 425984; i += stride) {
    if (i < 32768) {
      int n = i >> 8, k = i & 255;
      wgs[i] = (f16)((k < 128) ? Wg[k * 128 + n] : Ws[(k - 128) * 128 + n]);
    } else if (i < 98304) {
      int j = i - 32768, c = j >> 7, k = j & 127;
      wt1[j] = (f16)W1[k * 512 + c];
    } else if (i < 360448) {
      int j = i - 98304, c = j >> 9, k = j & 511;
      wt2[j] = (f16)W2[k * 512 + c];
    } else {
      int j = i - 360448, c = j >> 9, k = j & 511;
      wt3[j] = (f16)W3[k * 128 + c];
    }
  }
}

// ---- gather + mean -> Xc mean-half: 32 lanes/node, masked 8-wide batch ----
__global__ __launch_bounds__(256) void gather_xcat(
    const f16* __restrict__ z16, const int* __restrict__ row_start,
    const int* __restrict__ adj, f16* __restrict__ Xc, int N) {
  int node = (blockIdx.x * 256 + threadIdx.x) >> 5;
  if (node >= N) return;
  int lane = threadIdx.x & 31;
  int beg = row_start[node], end = row_start[node + 1];
  float a0 = 0, a1 = 0, a2 = 0, a3 = 0;
#pragma unroll
  for (int j = 0; j < 8; ++j) {
    int idx = beg + j;
    bool vld = idx < end;
    int nb = vld ? adj[idx] : node;
    f16x4 x = *(const f16x4*)(z16 + (long long)nb * 128 + 4 * lane);
    float w = vld ? 1.0f : 0.0f;
    a0 += w * (float)x[0]; a1 += w * (float)x[1];
    a2 += w * (float)x[2]; a3 += w * (float)x[3];
  }
  int i = beg + 8;
  if (i < end) {
    float b0 = 0, b1 = 0, b2 = 0, b3 = 0;
    float c0 = 0, c1 = 0, c2 = 0, c3 = 0;
    float d0 = 0, d1 = 0, d2 = 0, d3 = 0;
    for (; i + 4 <= end; i += 4) {
      int n0 = adj[i], n1 = adj[i + 1], n2 = adj[i + 2], n3 = adj[i + 3];
      f16x4 v0 = *(const f16x4*)(z16 + (long long)n0 * 128 + 4 * lane);
      f16x4 v1 = *(const f16x4*)(z16 + (long long)n1 * 128 + 4 * lane);
      f16x4 v2 = *(const f16x4*)(z16 + (long long)n2 * 128 + 4 * lane);
      f16x4 v3 = *(const f16x4*)(z16 + (long long)n3 * 128 + 4 * lane);
      a0 += (float)v0[0]; a1 += (float)v0[1]; a2 += (float)v0[2]; a3 += (float)v0[3];
      b0 += (float)v1[0]; b1 += (float)v1[1]; b2 += (float)v1[2]; b3 += (float)v1[3];
      c0 += (float)v2[0]; c1 += (float)v2[1]; c2 += (float)v2[2]; c3 += (float)v2[3];
      d0 += (float)v3[0]; d1 += (float)v3[1]; d2 += (float)v3[2]; d3 += (float)v3[3];
    }
    for (; i < end; ++i) {
      f16x4 v = *(const f16x4*)(z16 + (long long)adj[i] * 128 + 4 * lane);
      a0 += (float)v[0]; a1 += (float)v[1]; a2 += (float)v[2]; a3 += (float)v[3];
    }
    a0 += b0 + c0 + d0; a1 += b1 + c1 + d1;
    a2 += b2 + c2 + d2; a3 += b3 + c3 + d3;
  }
  int dg = end - beg;
  float inv = 1.0f / (float)(dg > 1 ? dg : 1);
  long long o = (long long)node * 256;
  f16x4 m;
  m[0] = (f16)(a0 * inv); m[1] = (f16)(a1 * inv);
  m[2] = (f16)(a2 * inv); m[3] = (f16)(a3 * inv);
  *(f16x4*)(Xc + o + 4 * lane) = m;
}

// ======================= fused L1+L2 (proven R10/R15) =======================
__global__ __launch_bounds__(256) void fused12(
    const f16* __restrict__ Xc, const f16* __restrict__ wgs,
    const f16* __restrict__ wt1, const float* __restrict__ bg,
    const float* __restrict__ b1, f16* __restrict__ h2) {
  __shared__ __align__(16) char L[49152];
  const int tid = threadIdx.x;
  const int wid = tid >> 6, lane = tid & 63;
  const int wm = wid & 1, wn = wid >> 1;  // 2x2
  const int lr = lane & 15, lq = lane >> 4;
  const int key = lr & 7;
  const long long m0 = (long long)blockIdx.x * 128;
  const f16* Ag = Xc + m0 * 256;

  f32x4 acc[4][4];
#pragma unroll
  for (int i = 0; i < 4; ++i)
#pragma unroll
    for (int j = 0; j < 4; ++j)
#pragma unroll
      for (int r = 0; r < 4; ++r) acc[i][j][r] = 0.0f;

#pragma unroll 1
  for (int k0 = 0; k0 < 256; k0 += 64) {
#pragma unroll
    for (int c = 0; c < 4; ++c) {
      int f = c * 256 + tid;
      int row = f >> 3, ss = (f & 7) ^ (row & 7);
      async_load16(Ag + (long long)row * 256 + k0 + ss * 8, L + f * 16);
    }
#pragma unroll
    for (int c = 0; c < 4; ++c) {
      int f = c * 256 + tid;
      int row = f >> 3, ss = (f & 7) ^ (row & 7);
      async_load16(wgs + row * 256 + k0 + ss * 8, L + 16384 + f * 16);
    }
    __syncthreads();
#pragma unroll
    for (int kk = 0; kk < 64; kk += 32) {
      const int co = (((kk >> 3) + lq) ^ key) * 16;
      f16x8 a[4], b[4];
#pragma unroll
      for (int i = 0; i < 4; ++i)
        a[i] = *reinterpret_cast<const f16x8*>(L + (wm * 64 + i * 16 + lr) * 128 + co);
#pragma unroll
      for (int j = 0; j < 4; ++j)
        b[j] = *reinterpret_cast<const f16x8*>(L + 16384 + (wn * 64 + j * 16 + lr) * 128 + co);
#pragma unroll
      for (int i = 0; i < 4; ++i)
#pragma unroll
        for (int j = 0; j < 4; ++j)
          acc[i][j] = __builtin_amdgcn_mfma_f32_16x16x32_f16(a[i], b[j], acc[i][j], 0, 0, 0);
    }
    __syncthreads();
  }

#pragma unroll
  for (int i = 0; i < 4; ++i)
#pragma unroll
    for (int j = 0; j < 4; ++j) {
      int col = wn * 64 + j * 16 + lr;
      float bv = bg[col];
#pragma unroll
      for (int r = 0; r < 4; ++r) {
        int row = wm * 64 + i * 16 + lq * 4 + r;
        float v = fmaxf(acc[i][j][r] + bv, 0.0f);
        *reinterpret_cast<f16*>(L + row * 256 + (((col >> 3) ^ (row & 7)) * 16) +
                                (col & 7) * 2) = (f16)v;
      }
    }
  __syncthreads();

#pragma unroll 1
  for (int cb = 0; cb < 4; ++cb) {
#pragma unroll
    for (int i = 0; i < 4; ++i)
#pragma unroll
      for (int j = 0; j < 4; ++j)
#pragma unroll
        for (int r = 0; r < 4; ++r) acc[i][j][r] = 0.0f;

#pragma unroll 1
    for (int kc = 0; kc < 2; ++kc) {
#pragma unroll
      for (int c = 0; c < 4; ++c) {
        int f = c * 256 + tid;
        int row = f >> 3, ss = (f & 7) ^ (row & 7);
        async_load16(wt1 + (long long)(cb * 128 + row) * 128 + kc * 64 + ss * 8,
                     L + 32768 + f * 16);
      }
      __syncthreads();
#pragma unroll
      for (int kk = 0; kk < 64; kk += 32) {
        const int aslot = kc * 8 + (kk >> 3) + lq;
        const int bco = (((kk >> 3) + lq) ^ key) * 16;
        f16x8 a[4], b[4];
#pragma unroll
        for (int i = 0; i < 4; ++i)
          a[i] = *reinterpret_cast<const f16x8*>(
              L + (wm * 64 + i * 16 + lr) * 256 + (aslot ^ key) * 16);
#pragma unroll
        for (int j = 0; j < 4; ++j)
          b[j] = *reinterpret_cast<const f16x8*>(
              L + 32768 + (wn * 64 + j * 16 + lr) * 128 + bco);
#pragma unroll
        for (int i = 0; i < 4; ++i)
#pragma unroll
          for (int j = 0; j < 4; ++j)
            acc[i][j] = __builtin_amdgcn_mfma_f32_16x16x32_f16(a[i], b[j], acc[i][j], 0, 0, 0);
      }
      __syncthreads();
    }
#pragma unroll
    for (int i = 0; i < 4; ++i)
#pragma unroll
      for (int j = 0; j < 4; ++j) {
        int colg = cb * 128 + wn * 64 + j * 16 + lr;
        float bv = b1[colg];
#pragma unroll
        for (int r = 0; r < 4; ++r) {
          long long row = m0 + wm * 64 + i * 16 + lq * 4 + r;
          h2[row * 512 + colg] = (f16)fast_tanh(acc[i][j][r] + bv);
        }
      }
  }
}

// --------- R5/R11 proven drain GEMM (BK=64, single buffer, swizzled) ----------
template <int K, int NOUT, int WM, int WN, int MI, int ACT, bool OUTF32>
__global__ __launch_bounds__(WM * WN * 64) void gemm_r(
    const f16* __restrict__ X, const f16* __restrict__ Wt,
    const float* __restrict__ bias, void* __restrict__ OutV, int M) {
  constexpr int NJ = 4;
  constexpr int BM = WM * MI * 16;
  constexpr int BN = WN * NJ * 16;
  constexpr int NTHR = WM * WN * 64;
  constexpr int CA = (BM * 128) / (NTHR * 16);
  constexpr int CB = (BN * 128) / (NTHR * 16);
  __shared__ __align__(16) f16 As[BM * 64];
  __shared__ __align__(16) f16 Bs[BN * 64];

  const int tid = threadIdx.x;
  const int wid = tid >> 6, lane = tid & 63;
  const int wm = wid / WN, wn = wid % WN;
  const int lr = lane & 15, lq = lane >> 4;
  const int rxor = lr & 7;
  const long long m0 = (long long)blockIdx.x * BM;
  const int n0 = blockIdx.y * BN;

  const f16* Ag = X + m0 * K;
  const f16* Bg = Wt + (long long)n0 * K;

  long long aOff[CA], bOff[CB];
#pragma unroll
  for (int c = 0; c < CA; ++c) {
    int f = c * NTHR + tid;
    int row = f >> 3, ss = (f & 7) ^ (row & 7);
    aOff[c] = (long long)row * K + ss * 8;
  }
#pragma unroll
  for (int c = 0; c < CB; ++c) {
    int f = c * NTHR + tid;
    int row = f >> 3, ss = (f & 7) ^ (row & 7);
    bOff[c] = (long long)row * K + ss * 8;
  }

  f32x4 acc[MI][NJ];
#pragma unroll
  for (int i = 0; i < MI; ++i)
#pragma unroll
    for (int j = 0; j < NJ; ++j)
#pragma unroll
      for (int r = 0; r < 4; ++r) acc[i][j][r] = 0.0f;

#pragma unroll 1
  for (int k0 = 0; k0 < K; k0 += 64) {
#pragma unroll
    for (int c = 0; c < CA; ++c)
      async_load16(Ag + aOff[c] + k0, (char*)As + c * NTHR * 16 + wid * 1024);
#pragma unroll
    for (int c = 0; c < CB; ++c)
      async_load16(Bg + bOff[c] + k0, (char*)Bs + c * NTHR * 16 + wid * 1024);
    __syncthreads();
#pragma unroll
    for (int kk = 0; kk < 64; kk += 32) {
      const int co = (((kk >> 3) + lq) ^ rxor) * 16;
      f16x8 a[MI], b[NJ];
#pragma unroll
      for (int i = 0; i < MI; ++i)
        a[i] = *reinterpret_cast<const f16x8*>(
            (const char*)As + (wm * MI * 16 + i * 16 + lr) * 128 + co);
#pragma unroll
      for (int j = 0; j < NJ; ++j)
        b[j] = *reinterpret_cast<const f16x8*>(
            (const char*)Bs + (wn * NJ * 16 + j * 16 + lr) * 128 + co);
#pragma unroll
      for (int i = 0; i < MI; ++i)
#pragma unroll
        for (int j = 0; j < NJ; ++j)
          acc[i][j] = __builtin_amdgcn_mfma_f32_16x16x32_f16(a[i], b[j], acc[i][j], 0, 0, 0);
    }
    __syncthreads();
  }

#pragma unroll
  for (int i = 0; i < MI; ++i) {
#pragma unroll
    for (int j = 0; j < NJ; ++j) {
      int col = n0 + wn * NJ * 16 + j * 16 + lr;
      float bv = bias[col];
#pragma unroll
      for (int r = 0; r < 4; ++r) {
        long long row = m0 + wm * MI * 16 + i * 16 + lq * 4 + r;
        if (row < M) {
          float v = acc[i][j][r] + bv;
          if (ACT == 1) v = fmaxf(v, 0.0f);
          else if (ACT == 2) v = fast_tanh(v);
          if constexpr (OUTF32)
            ((float*)OutV)[row * NOUT + col] = v;
          else
            ((f16*)OutV)[row * NOUT + col] = (f16)v;
        }
      }
    }
  }
}

extern "C" void kernel_launch(void* const* d_in, const int* in_sizes, int n_in,
                              void* d_out, int out_size, void* d_ws, size_t ws_size,
                              hipStream_t stream) {
  const float* z  = (const float*)d_in[0];
  const int*   ei = (const int*)d_in[1];
  const float* Wg = (const float*)d_in[2];
  const float* Ws = (const float*)d_in[3];
  const float* bg = (const float*)d_in[4];
  const float* W1 = (const float*)d_in[5];
  const float* b1 = (const float*)d_in[6];
  const float* W2 = (const float*)d_in[7];
  const float* b2 = (const float*)d_in[8];
  const float* W3 = (const float*)d_in[9];
  const float* b3 = (const float*)d_in[10];

  const int Nn = in_sizes[0] / 128;
  const int E  = in_sizes[1] / 2;
  const int* src = ei;
  const int* dst = ei + E;
  const int nb = (Nn + 1023) / 1024;
  const int gm256 = (Nn + 255) / 256;        // 256-row tiles (gemm3/gemm4)
  const long long Mpad = (long long)gm256 * 256;
  const int gm128 = gm256 * 2;               // 128-row tiles (fused12)

  // workspace overlay (peak ~207 MB):
  //   [0, 51.2M)        Xc    (prep/gather -> fused12)
  //   [51.2, ~81M)      CSR + z16 (dead after gather)
  //   [0, 102.4M)       h3    (gemm3 -> gemm4; overlays Xc+CSR+z16, all dead)
  //   [102.4, 204.8M)   h2    (fused12 -> gemm3)
  //   [204.8M, ...)     prepped weights (~1.7 MB)
  char* base = (char*)d_ws;
  const size_t XCB = (size_t)Mpad * 256 * 2;
  const size_t H3B = (size_t)Mpad * 512 * 2;
  f16* Xc = (f16*)(base);
  f16* h3 = (f16*)(base);
  size_t off = XCB;
  auto alloc = [&](size_t b) -> void* {
    void* p = base + off;
    off += (b + 255) & ~(size_t)255;
    return p;
  };
  int* degi      = (int*)alloc((size_t)Nn * 4);
  int* row_start = (int*)alloc((size_t)(Nn + 1) * 4);
  int* cursor    = (int*)alloc((size_t)Nn * 4);
  int* adj       = (int*)alloc((size_t)(E + 8) * 4);  // +8 pad for masked batch
  int* bsum      = (int*)alloc((size_t)nb * 4);
  f16* z16       = (f16*)alloc((size_t)Nn * 128 * 2);
  off = H3B;  // h2 after h3 span
  f16* h2  = (f16*)alloc((size_t)Mpad * 512 * 2);
  f16* wgs = (f16*)alloc((size_t)128 * 256 * 2);
  f16* wt1 = (f16*)alloc((size_t)512 * 128 * 2);
  f16* wt2 = (f16*)alloc((size_t)512 * 512 * 2);
  f16* wt3 = (f16*)alloc((size_t)128 * 512 * 2);

  // CSR + prep
  hipMemsetAsync(degi, 0, (size_t)Nn * 4, stream);
  fused_prep<<<2048, 256, 0, stream>>>(dst, degi, E, Wg, Ws, W1, W2, W3,
                                       wgs, wt1, wt2, wt3, z, z16, Xc, Nn * 32);
  scan_partial<<<nb, 256, 0, stream>>>(degi, bsum, Nn);
  scan_final<<<nb, 256, 0, stream>>>(degi, bsum, row_start, cursor, nb, Nn, E);
  fill_adj<<<(E + 255) / 256, 256, 0, stream>>>(src, dst, cursor, adj, E);

  // gather mean-half
  {
    long long tot = (long long)Nn * 32;
    gather_xcat<<<(int)((tot + 255) / 256), 256, 0, stream>>>(z16, row_start, adj, Xc, Nn);
  }

  // MLP: fused L1+L2; gemm3 1024-thr BM=BN=256; gemm4 512-thr BM=256.
  fused12<<<gm128, 256, 0, stream>>>(Xc, wgs, wt1, bg, b1, h2);
  gemm_r<512, 512, 4, 4, 4, 2, false><<<dim3(gm256, 2), 1024, 0, stream>>>(h2, wt2, b2, (void*)h3, Nn);
  gemm_r<512, 128, 4, 2, 4, 0, true><<<dim3(gm256, 1), 512, 0, stream>>>(h3, wt3, b3, d_out, Nn);
}

// Round 17
// 312.372 us; speedup vs baseline: 1.4339x; 1.0184x over previous
//
#include <hip/hip_runtime.h>
#include <hip/hip_fp16.h>

// GDE func: out = MLP(relu(mean_agg(z,edges)@Wg + z@Ws + bg))
// Round 16 -> 17: surgical revert of the one R16 regression: gemm3 back to
// proven <WM=2,WN=4> 512-thr BM=128/BN=256 (94us across R13/R15; the R16
// 1024-thr variant hit the same 33% occupancy but with 16-wave barrier
// granularity -> 107us). Keep R16's wins: gemm4 BM=256, CSR trims
// (memsetAsync + folded scan), fused12, masked-8 gather, fused_prep.

typedef _Float16 f16;
typedef __attribute__((ext_vector_type(4))) _Float16 f16x4;
typedef __attribute__((ext_vector_type(8))) _Float16 f16x8;
typedef __attribute__((ext_vector_type(4))) float f32x4;

__device__ __forceinline__ void async_load16(const void* g, void* lds) {
  __builtin_amdgcn_global_load_lds(
      (const __attribute__((address_space(1))) void*)g,
      (__attribute__((address_space(3))) void*)lds, 16, 0, 0);
}

__device__ __forceinline__ float fast_tanh(float x) {
  float a = fabsf(x);
  float e = __expf(-2.0f * a);
  float r = (1.0f - e) * __builtin_amdgcn_rcpf(1.0f + e);
  return copysignf(r, x);
}

// ---- CSR scan ----
__global__ __launch_bounds__(256) void scan_partial(const int* __restrict__ degi,
                                                    int* __restrict__ bsum, int N) {
  __shared__ int lds[256];
  int b = blockIdx.x, t = threadIdx.x;
  int s = 0;
#pragma unroll
  for (int j = 0; j < 4; ++j) {
    int idx = b * 1024 + t * 4 + j;
    if (idx < N) s += degi[idx];
  }
  lds[t] = s;
  __syncthreads();
  for (int off = 128; off > 0; off >>= 1) {
    if (t < off) lds[t] += lds[t + off];
    __syncthreads();
  }
  if (t == 0) bsum[b] = lds[0];
}

// scan_final with inlined block-offset reduction (replaces scan_bsums)
__global__ __launch_bounds__(256) void scan_final(
    const int* __restrict__ degi, const int* __restrict__ bsum,
    int* __restrict__ row_start, int* __restrict__ cursor, int nb, int N, int E) {
  __shared__ int lds[256];
  __shared__ int sboff;
  int b = blockIdx.x, t = threadIdx.x;
  lds[t] = (t < b && t < nb) ? bsum[t] : 0;
  __syncthreads();
  for (int off = 128; off > 0; off >>= 1) {
    if (t < off) lds[t] += lds[t + off];
    __syncthreads();
  }
  if (t == 0) {
    sboff = lds[0];
    if (b == 0) row_start[N] = E;
  }
  __syncthreads();

  int base = b * 1024;
  int v[4];
  int s = 0;
#pragma unroll
  for (int j = 0; j < 4; ++j) {
    int idx = base + t * 4 + j;
    v[j] = (idx < N) ? degi[idx] : 0;
    s += v[j];
  }
  lds[t] = s;
  __syncthreads();
  for (int off = 1; off < 256; off <<= 1) {
    int x = lds[t];
    int y = (t >= off) ? lds[t - off] : 0;
    __syncthreads();
    lds[t] = x + y;
    __syncthreads();
  }
  int pre = sboff + lds[t] - s;
#pragma unroll
  for (int j = 0; j < 4; ++j) {
    int idx = base + t * 4 + j;
    if (idx < N) { row_start[idx] = pre; cursor[idx] = pre; pre += v[j]; }
  }
}

__global__ __launch_bounds__(256) void fill_adj(const int* __restrict__ src,
                                                const int* __restrict__ dst,
                                                int* __restrict__ cursor,
                                                int* __restrict__ adj, int E) {
  int e = blockIdx.x * 256 + threadIdx.x;
  if (e >= E) return;
  int p = atomicAdd(&cursor[dst[e]], 1);
  adj[p] = src[e];
}

// ---- merged: deg_count + weight prep + z16 cast (+Xc z-half) ----
__global__ __launch_bounds__(256) void fused_prep(
    const int* __restrict__ dst, int* __restrict__ degi, int E,
    const float* __restrict__ Wg, const float* __restrict__ Ws,
    const float* __restrict__ W1, const float* __restrict__ W2,
    const float* __restrict__ W3, f16* __restrict__ wgs, f16* __restrict__ wt1,
    f16* __restrict__ wt2, f16* __restrict__ wt3,
    const float* __restrict__ z, f16* __restrict__ z16, f16* __restrict__ Xc,
    int n4) {
  int i0 = blockIdx.x * 256 + threadIdx.x;
  int stride = gridDim.x * 256;
  for (int i = i0; i < n4; i += stride) {
    float4 v = *(const float4*)(z + 4 * (long long)i);
    f16x4 c;
    c[0] = (f16)v.x; c[1] = (f16)v.y; c[2] = (f16)v.z; c[3] = (f16)v.w;
    *(f16x4*)(z16 + 4 * (long long)i) = c;
    int node = i >> 5, sl = i & 31;
    *(f16x4*)(Xc + (long long)node * 256 + 128 + 4 * sl) = c;
  }
  for (int i = i0; i < E; i += stride) atomicAdd(&degi[dst[i]], 1);
  for (int i = i0; i < 425984; i += stride) {
    if (i < 32768) {
      int n = i >> 8, k = i & 255;
      wgs[i] = (f16)((k < 128) ? Wg[k * 128 + n] : Ws[(k - 128) * 128 + n]);
    } else if (i < 98304) {
      int j = i - 32768, c = j >> 7, k = j & 127;
      wt1[j] = (f16)W1[k * 512 + c];
    } else if (i < 360448) {
      int j = i - 98304, c = j >> 9, k = j & 511;
      wt2[j] = (f16)W2[k * 512 + c];
    } else {
      int j = i - 360448, c = j >> 9, k = j & 511;
      wt3[j] = (f16)W3[k * 128 + c];
    }
  }
}

// ---- gather + mean -> Xc mean-half: 32 lanes/node, masked 8-wide batch ----
__global__ __launch_bounds__(256) void gather_xcat(
    const f16* __restrict__ z16, const int* __restrict__ row_start,
    const int* __restrict__ adj, f16* __restrict__ Xc, int N) {
  int node = (blockIdx.x * 256 + threadIdx.x) >> 5;
  if (node >= N) return;
  int lane = threadIdx.x & 31;
  int beg = row_start[node], end = row_start[node + 1];
  float a0 = 0, a1 = 0, a2 = 0, a3 = 0;
#pragma unroll
  for (int j = 0; j < 8; ++j) {
    int idx = beg + j;
    bool vld = idx < end;
    int nb = vld ? adj[idx] : node;
    f16x4 x = *(const f16x4*)(z16 + (long long)nb * 128 + 4 * lane);
    float w = vld ? 1.0f : 0.0f;
    a0 += w * (float)x[0]; a1 += w * (float)x[1];
    a2 += w * (float)x[2]; a3 += w * (float)x[3];
  }
  int i = beg + 8;
  if (i < end) {
    float b0 = 0, b1 = 0, b2 = 0, b3 = 0;
    float c0 = 0, c1 = 0, c2 = 0, c3 = 0;
    float d0 = 0, d1 = 0, d2 = 0, d3 = 0;
    for (; i + 4 <= end; i += 4) {
      int n0 = adj[i], n1 = adj[i + 1], n2 = adj[i + 2], n3 = adj[i + 3];
      f16x4 v0 = *(const f16x4*)(z16 + (long long)n0 * 128 + 4 * lane);
      f16x4 v1 = *(const f16x4*)(z16 + (long long)n1 * 128 + 4 * lane);
      f16x4 v2 = *(const f16x4*)(z16 + (long long)n2 * 128 + 4 * lane);
      f16x4 v3 = *(const f16x4*)(z16 + (long long)n3 * 128 + 4 * lane);
      a0 += (float)v0[0]; a1 += (float)v0[1]; a2 += (float)v0[2]; a3 += (float)v0[3];
      b0 += (float)v1[0]; b1 += (float)v1[1]; b2 += (float)v1[2]; b3 += (float)v1[3];
      c0 += (float)v2[0]; c1 += (float)v2[1]; c2 += (float)v2[2]; c3 += (float)v2[3];
      d0 += (float)v3[0]; d1 += (float)v3[1]; d2 += (float)v3[2]; d3 += (float)v3[3];
    }
    for (; i < end; ++i) {
      f16x4 v = *(const f16x4*)(z16 + (long long)adj[i] * 128 + 4 * lane);
      a0 += (float)v[0]; a1 += (float)v[1]; a2 += (float)v[2]; a3 += (float)v[3];
    }
    a0 += b0 + c0 + d0; a1 += b1 + c1 + d1;
    a2 += b2 + c2 + d2; a3 += b3 + c3 + d3;
  }
  int dg = end - beg;
  float inv = 1.0f / (float)(dg > 1 ? dg : 1);
  long long o = (long long)node * 256;
  f16x4 m;
  m[0] = (f16)(a0 * inv); m[1] = (f16)(a1 * inv);
  m[2] = (f16)(a2 * inv); m[3] = (f16)(a3 * inv);
  *(f16x4*)(Xc + o + 4 * lane) = m;
}

// ======================= fused L1+L2 (proven R10/R15) =======================
__global__ __launch_bounds__(256) void fused12(
    const f16* __restrict__ Xc, const f16* __restrict__ wgs,
    const f16* __restrict__ wt1, const float* __restrict__ bg,
    const float* __restrict__ b1, f16* __restrict__ h2) {
  __shared__ __align__(16) char L[49152];
  const int tid = threadIdx.x;
  const int wid = tid >> 6, lane = tid & 63;
  const int wm = wid & 1, wn = wid >> 1;  // 2x2
  const int lr = lane & 15, lq = lane >> 4;
  const int key = lr & 7;
  const long long m0 = (long long)blockIdx.x * 128;
  const f16* Ag = Xc + m0 * 256;

  f32x4 acc[4][4];
#pragma unroll
  for (int i = 0; i < 4; ++i)
#pragma unroll
    for (int j = 0; j < 4; ++j)
#pragma unroll
      for (int r = 0; r < 4; ++r) acc[i][j][r] = 0.0f;

#pragma unroll 1
  for (int k0 = 0; k0 < 256; k0 += 64) {
#pragma unroll
    for (int c = 0; c < 4; ++c) {
      int f = c * 256 + tid;
      int row = f >> 3, ss = (f & 7) ^ (row & 7);
      async_load16(Ag + (long long)row * 256 + k0 + ss * 8, L + f * 16);
    }
#pragma unroll
    for (int c = 0; c < 4; ++c) {
      int f = c * 256 + tid;
      int row = f >> 3, ss = (f & 7) ^ (row & 7);
      async_load16(wgs + row * 256 + k0 + ss * 8, L + 16384 + f * 16);
    }
    __syncthreads();
#pragma unroll
    for (int kk = 0; kk < 64; kk += 32) {
      const int co = (((kk >> 3) + lq) ^ key) * 16;
      f16x8 a[4], b[4];
#pragma unroll
      for (int i = 0; i < 4; ++i)
        a[i] = *reinterpret_cast<const f16x8*>(L + (wm * 64 + i * 16 + lr) * 128 + co);
#pragma unroll
      for (int j = 0; j < 4; ++j)
        b[j] = *reinterpret_cast<const f16x8*>(L + 16384 + (wn * 64 + j * 16 + lr) * 128 + co);
#pragma unroll
      for (int i = 0; i < 4; ++i)
#pragma unroll
        for (int j = 0; j < 4; ++j)
          acc[i][j] = __builtin_amdgcn_mfma_f32_16x16x32_f16(a[i], b[j], acc[i][j], 0, 0, 0);
    }
    __syncthreads();
  }

#pragma unroll
  for (int i = 0; i < 4; ++i)
#pragma unroll
    for (int j = 0; j < 4; ++j) {
      int col = wn * 64 + j * 16 + lr;
      float bv = bg[col];
#pragma unroll
      for (int r = 0; r < 4; ++r) {
        int row = wm * 64 + i * 16 + lq * 4 + r;
        float v = fmaxf(acc[i][j][r] + bv, 0.0f);
        *reinterpret_cast<f16*>(L + row * 256 + (((col >> 3) ^ (row & 7)) * 16) +
                                (col & 7) * 2) = (f16)v;
      }
    }
  __syncthreads();

#pragma unroll 1
  for (int cb = 0; cb < 4; ++cb) {
#pragma unroll
    for (int i = 0; i < 4; ++i)
#pragma unroll
      for (int j = 0; j < 4; ++j)
#pragma unroll
        for (int r = 0; r < 4; ++r) acc[i][j][r] = 0.0f;

#pragma unroll 1
    for (int kc = 0; kc < 2; ++kc) {
#pragma unroll
      for (int c = 0; c < 4; ++c) {
        int f = c * 256 + tid;
        int row = f >> 3, ss = (f & 7) ^ (row & 7);
        async_load16(wt1 + (long long)(cb * 128 + row) * 128 + kc * 64 + ss * 8,
                     L + 32768 + f * 16);
      }
      __syncthreads();
#pragma unroll
      for (int kk = 0; kk < 64; kk += 32) {
        const int aslot = kc * 8 + (kk >> 3) + lq;
        const int bco = (((kk >> 3) + lq) ^ key) * 16;
        f16x8 a[4], b[4];
#pragma unroll
        for (int i = 0; i < 4; ++i)
          a[i] = *reinterpret_cast<const f16x8*>(
              L + (wm * 64 + i * 16 + lr) * 256 + (aslot ^ key) * 16);
#pragma unroll
        for (int j = 0; j < 4; ++j)
          b[j] = *reinterpret_cast<const f16x8*>(
              L + 32768 + (wn * 64 + j * 16 + lr) * 128 + bco);
#pragma unroll
        for (int i = 0; i < 4; ++i)
#pragma unroll
          for (int j = 0; j < 4; ++j)
            acc[i][j] = __builtin_amdgcn_mfma_f32_16x16x32_f16(a[i], b[j], acc[i][j], 0, 0, 0);
      }
      __syncthreads();
    }
#pragma unroll
    for (int i = 0; i < 4; ++i)
#pragma unroll
      for (int j = 0; j < 4; ++j) {
        int colg = cb * 128 + wn * 64 + j * 16 + lr;
        float bv = b1[colg];
#pragma unroll
        for (int r = 0; r < 4; ++r) {
          long long row = m0 + wm * 64 + i * 16 + lq * 4 + r;
          h2[row * 512 + colg] = (f16)fast_tanh(acc[i][j][r] + bv);
        }
      }
  }
}

// --------- R5/R11 proven drain GEMM (BK=64, single buffer, swizzled) ----------
template <int K, int NOUT, int WM, int WN, int MI, int ACT, bool OUTF32>
__global__ __launch_bounds__(WM * WN * 64) void gemm_r(
    const f16* __restrict__ X, const f16* __restrict__ Wt,
    const float* __restrict__ bias, void* __restrict__ OutV, int M) {
  constexpr int NJ = 4;
  constexpr int BM = WM * MI * 16;
  constexpr int BN = WN * NJ * 16;
  constexpr int NTHR = WM * WN * 64;
  constexpr int CA = (BM * 128) / (NTHR * 16);
  constexpr int CB = (BN * 128) / (NTHR * 16);
  __shared__ __align__(16) f16 As[BM * 64];
  __shared__ __align__(16) f16 Bs[BN * 64];

  const int tid = threadIdx.x;
  const int wid = tid >> 6, lane = tid & 63;
  const int wm = wid / WN, wn = wid % WN;
  const int lr = lane & 15, lq = lane >> 4;
  const int rxor = lr & 7;
  const long long m0 = (long long)blockIdx.x * BM;
  const int n0 = blockIdx.y * BN;

  const f16* Ag = X + m0 * K;
  const f16* Bg = Wt + (long long)n0 * K;

  long long aOff[CA], bOff[CB];
#pragma unroll
  for (int c = 0; c < CA; ++c) {
    int f = c * NTHR + tid;
    int row = f >> 3, ss = (f & 7) ^ (row & 7);
    aOff[c] = (long long)row * K + ss * 8;
  }
#pragma unroll
  for (int c = 0; c < CB; ++c) {
    int f = c * NTHR + tid;
    int row = f >> 3, ss = (f & 7) ^ (row & 7);
    bOff[c] = (long long)row * K + ss * 8;
  }

  f32x4 acc[MI][NJ];
#pragma unroll
  for (int i = 0; i < MI; ++i)
#pragma unroll
    for (int j = 0; j < NJ; ++j)
#pragma unroll
      for (int r = 0; r < 4; ++r) acc[i][j][r] = 0.0f;

#pragma unroll 1
  for (int k0 = 0; k0 < K; k0 += 64) {
#pragma unroll
    for (int c = 0; c < CA; ++c)
      async_load16(Ag + aOff[c] + k0, (char*)As + c * NTHR * 16 + wid * 1024);
#pragma unroll
    for (int c = 0; c < CB; ++c)
      async_load16(Bg + bOff[c] + k0, (char*)Bs + c * NTHR * 16 + wid * 1024);
    __syncthreads();
#pragma unroll
    for (int kk = 0; kk < 64; kk += 32) {
      const int co = (((kk >> 3) + lq) ^ rxor) * 16;
      f16x8 a[MI], b[NJ];
#pragma unroll
      for (int i = 0; i < MI; ++i)
        a[i] = *reinterpret_cast<const f16x8*>(
            (const char*)As + (wm * MI * 16 + i * 16 + lr) * 128 + co);
#pragma unroll
      for (int j = 0; j < NJ; ++j)
        b[j] = *reinterpret_cast<const f16x8*>(
            (const char*)Bs + (wn * NJ * 16 + j * 16 + lr) * 128 + co);
#pragma unroll
      for (int i = 0; i < MI; ++i)
#pragma unroll
        for (int j = 0; j < NJ; ++j)
          acc[i][j] = __builtin_amdgcn_mfma_f32_16x16x32_f16(a[i], b[j], acc[i][j], 0, 0, 0);
    }
    __syncthreads();
  }

#pragma unroll
  for (int i = 0; i < MI; ++i) {
#pragma unroll
    for (int j = 0; j < NJ; ++j) {
      int col = n0 + wn * NJ * 16 + j * 16 + lr;
      float bv = bias[col];
#pragma unroll
      for (int r = 0; r < 4; ++r) {
        long long row = m0 + wm * MI * 16 + i * 16 + lq * 4 + r;
        if (row < M) {
          float v = acc[i][j][r] + bv;
          if (ACT == 1) v = fmaxf(v, 0.0f);
          else if (ACT == 2) v = fast_tanh(v);
          if constexpr (OUTF32)
            ((float*)OutV)[row * NOUT + col] = v;
          else
            ((f16*)OutV)[row * NOUT + col] = (f16)v;
        }
      }
    }
  }
}

extern "C" void kernel_launch(void* const* d_in, const int* in_sizes, int n_in,
                              void* d_out, int out_size, void* d_ws, size_t ws_size,
                              hipStream_t stream) {
  const float* z  = (const float*)d_in[0];
  const int*   ei = (const int*)d_in[1];
  const float* Wg = (const float*)d_in[2];
  const float* Ws = (const float*)d_in[3];
  const float* bg = (const float*)d_in[4];
  const float* W1 = (const float*)d_in[5];
  const float* b1 = (const float*)d_in[6];
  const float* W2 = (const float*)d_in[7];
  const float* b2 = (const float*)d_in[8];
  const float* W3 = (const float*)d_in[9];
  const float* b3 = (const float*)d_in[10];

  const int Nn = in_sizes[0] / 128;
  const int E  = in_sizes[1] / 2;
  const int* src = ei;
  const int* dst = ei + E;
  const int nb = (Nn + 1023) / 1024;
  const int gm256 = (Nn + 255) / 256;        // 256-row tiles (gemm4)
  const long long Mpad = (long long)gm256 * 256;
  const int gm128 = gm256 * 2;               // 128-row tiles (fused12, gemm3)

  // workspace overlay (peak ~207 MB):
  //   [0, 51.2M)        Xc    (prep/gather -> fused12)
  //   [51.2, ~81M)      CSR + z16 (dead after gather)
  //   [0, 102.4M)       h3    (gemm3 -> gemm4; overlays Xc+CSR+z16, all dead)
  //   [102.4, 204.8M)   h2    (fused12 -> gemm3)
  //   [204.8M, ...)     prepped weights (~1.7 MB)
  char* base = (char*)d_ws;
  const size_t XCB = (size_t)Mpad * 256 * 2;
  const size_t H3B = (size_t)Mpad * 512 * 2;
  f16* Xc = (f16*)(base);
  f16* h3 = (f16*)(base);
  size_t off = XCB;
  auto alloc = [&](size_t b) -> void* {
    void* p = base + off;
    off += (b + 255) & ~(size_t)255;
    return p;
  };
  int* degi      = (int*)alloc((size_t)Nn * 4);
  int* row_start = (int*)alloc((size_t)(Nn + 1) * 4);
  int* cursor    = (int*)alloc((size_t)Nn * 4);
  int* adj       = (int*)alloc((size_t)(E + 8) * 4);  // +8 pad for masked batch
  int* bsum      = (int*)alloc((size_t)nb * 4);
  f16* z16       = (f16*)alloc((size_t)Nn * 128 * 2);
  off = H3B;  // h2 after h3 span
  f16* h2  = (f16*)alloc((size_t)Mpad * 512 * 2);
  f16* wgs = (f16*)alloc((size_t)128 * 256 * 2);
  f16* wt1 = (f16*)alloc((size_t)512 * 128 * 2);
  f16* wt2 = (f16*)alloc((size_t)512 * 512 * 2);
  f16* wt3 = (f16*)alloc((size_t)128 * 512 * 2);

  // CSR + prep
  hipMemsetAsync(degi, 0, (size_t)Nn * 4, stream);
  fused_prep<<<2048, 256, 0, stream>>>(dst, degi, E, Wg, Ws, W1, W2, W3,
                                       wgs, wt1, wt2, wt3, z, z16, Xc, Nn * 32);
  scan_partial<<<nb, 256, 0, stream>>>(degi, bsum, Nn);
  scan_final<<<nb, 256, 0, stream>>>(degi, bsum, row_start, cursor, nb, Nn, E);
  fill_adj<<<(E + 255) / 256, 256, 0, stream>>>(src, dst, cursor, adj, E);

  // gather mean-half
  {
    long long tot = (long long)Nn * 32;
    gather_xcat<<<(int)((tot + 255) / 256), 256, 0, stream>>>(z16, row_start, adj, Xc, Nn);
  }

  // MLP: fused L1+L2; gemm3 proven 512-thr BM=128/BN=256; gemm4 BM=256.
  fused12<<<gm128, 256, 0, stream>>>(Xc, wgs, wt1, bg, b1, h2);
  gemm_r<512, 512, 2, 4, 4, 2, false><<<dim3(gm128, 2), 512, 0, stream>>>(h2, wt2, b2, (void*)h3, Nn);
  gemm_r<512, 128, 4, 2, 4, 0, true><<<dim3(gm256, 1), 512, 0, stream>>>(h3, wt3, b3, d_out, Nn);
}